// Round 5
// baseline (262.228 us; speedup 1.0000x reference)
//
#include <hip/hip_runtime.h>
#include <hip/hip_bf16.h>

#define B_   32
#define C_   64
#define H_   96
#define W_   96
#define K_   32
#define R_   13
#define HO_  84
#define WO_  84
#define HW_  (H_*W_)      // 9216
#define OHW_ (HO_*WO_)    // 7056
#define CRR_ (C_*R_*R_)   // 10816
#define RR_  (R_*R_)      // 169

#define TILE_ 16
#define PW_   28          // patch height/width = TILE_+12
#define NPIX_ (PW_*PW_)   // 784
#define REGB_ (NPIX_*16)  // 12544 bytes: one ks-half region (8ch/pixel), pixel-major
#define LDS_BYTES (2*REGB_) // 25088: 16ch/pass -> 6 blocks/CU

typedef unsigned int u32;
typedef unsigned short u16;
typedef __attribute__((ext_vector_type(16))) float f32x16;
typedef __attribute__((ext_vector_type(4))) u32 u32x4;

static __device__ __forceinline__ u16 f2bf(float v){
    __hip_bfloat16 h = __float2bfloat16(v);  // RNE
    return *reinterpret_cast<u16*>(&h);
}

// D = A*B + D  (32x32x16 bf16)
#define MFMA(acc, a, b) asm("v_mfma_f32_32x32x16_bf16 %0, %1, %2, %0" \
                            : "+v"(acc) : "v"(a), "v"(b))

// ---------------- k1: y-norms + bf16 prototype tensor ----------------------
// u_g layout: [pass(4)][jx(13)][i(13)] slices of 1KB; within slice:
// byte = k*32 + ks*16 + e*2  where element e of half ks = channel cbase+ks*8+e.
// A-frag: lane(kpr,ks) reads 16B at slice + kpr*32 + ks*16.
__global__ void k_prep_y(const float* __restrict__ y, unsigned char* __restrict__ u_g){
    int k = blockIdx.x, tid = threadIdx.x;
    const float* yk = y + (size_t)k * CRR_;
    float ss = 0.f;
    for (int idx = tid; idx < CRR_; idx += 256){ float v = yk[idx]; ss += v*v; }
    for (int off = 32; off; off >>= 1) ss += __shfl_down(ss, off);
    __shared__ float red[4];
    if ((tid & 63) == 0) red[tid >> 6] = ss;
    __syncthreads();
    float inv = 1.f / fmaxf(sqrtf(red[0]+red[1]+red[2]+red[3]), 1e-9f);

    int c = tid & 63, grp = tid >> 6;                 // 64 c-lanes x 4 ij-groups
    int inoff = (k << 5) | ((c & 15) << 1);           // k*32 + (ks*8+e)*2
    for (int base = 0; base < RR_; base += 4){
        int ij = base + grp;
        if (ij < RR_){
            int i = ij / R_, jx = ij % R_;
            float v = yk[c*RR_ + ij] * inv;
            size_t slice = ((size_t)(c >> 4) * RR_ + jx*R_ + i) << 10;
            *(u16*)(u_g + slice + inoff) = f2bf(v);
        }
    }
}

// ---------------- k2: s[b,y,x] = sum_c x^2 (fp32 exact) --------------------
__global__ void k_sq(const float* __restrict__ x, float* __restrict__ s){
    int idx = blockIdx.x*256 + threadIdx.x;           // < 294912 exact
    int b = idx / HW_, r = idx % HW_;
    const float* xb = x + (size_t)b * C_ * HW_;
    float acc = 0.f;
    #pragma unroll
    for (int c = 0; c < C_; ++c){ float v = xb[(size_t)c*HW_ + r]; acc += v*v; }
    s[idx] = acc;
}

// ---------------- k3: inv_xn = 1/max(sqrt(13x13 box sum), eps) -------------
__global__ void k_inv(const float* __restrict__ s, float* __restrict__ inv_xn){
    int idx = blockIdx.x*256 + threadIdx.x;           // < 225792 exact
    int b = idx / OHW_, r = idx % OHW_;
    int oh = r / WO_, ow = r % WO_;
    const float* sb = s + (size_t)b*HW_ + oh*W_ + ow;
    float acc = 0.f;
    for (int i = 0; i < R_; ++i){
        #pragma unroll
        for (int j = 0; j < R_; ++j) acc += sb[i*W_ + j];
    }
    inv_xn[idx] = 1.f / fmaxf(sqrtf(acc), 1e-9f);
}

// ---------------- k_main: fused cosine-similarity conv ---------------------
// Block: 1 image x 16x16 tile, 256 thr (4 waves), 4 channel-passes (16ch).
// LDS 25088B -> 6 blocks/CU = 24 waves/CU (TLP hides LDS/L1 latency).
// Wave owns rows 4wv+rb+{0,2} (2 frags). jx outer / i inner, 4-deep rolling
// D-register window (load-to-use 2 iters): 15 LDS b128 per jx per wave.
// A (y tap slice) from global (L1-resident, 1KB/tap), prefetched 2 taps ahead.
__launch_bounds__(256, 6)
__global__ void k_main(const float* __restrict__ x, const unsigned char* __restrict__ u_g,
                       const float* __restrict__ inv_xn, float* __restrict__ out){
    extern __shared__ unsigned char lds[];

    int bb = blockIdx.x;
    int b  = bb / 36;
    int tt = bb % 36;
    int oy = (tt / 6) * TILE_;
    int ox = (tt % 6) * TILE_;

    int tid  = threadIdx.x;
    int lane = tid & 63;
    int wv   = tid >> 6;        // 0..3
    int ks   = lane >> 5;       // k-half of MFMA operands
    int rb   = (lane >> 4) & 1; // row within a frag's 2-row strip
    int cx   = lane & 15;       // col
    int kpr  = lane & 31;       // prototype row for A-frag

    const float* xb = x + (size_t)b * C_ * HW_;
    int aoff = (kpr << 5) + (ks << 4);      // A lane offset within 1KB slice
    int pb   = (4*wv + rb) * PW_ + cx;      // frag0 base pixel; frag1 = +2*PW_

    f32x16 acc0 = {}, acc1 = {};

    for (int pass = 0; pass < 4; ++pass){
        if (pass) __syncthreads();          // prior-pass reads done
        int cbase = pass << 4;
        // ---- stage 16 channels: fp32 global -> bf16 LDS, pixel-major ----
        for (int p = tid; p < NPIX_; p += 256){
            int py = p / PW_, px = p % PW_;
            int gy = oy + py; if (gy > H_-1) gy = H_-1;  // clamp feeds only invalid outputs
            int gx = ox + px; if (gx > W_-1) gx = W_-1;
            const float* src = xb + (size_t)cbase*HW_ + gy*W_ + gx;
            u32 w0 = f2bf(src[0*HW_])  | ((u32)f2bf(src[1*HW_])  << 16);
            u32 w1 = f2bf(src[2*HW_])  | ((u32)f2bf(src[3*HW_])  << 16);
            u32 w2 = f2bf(src[4*HW_])  | ((u32)f2bf(src[5*HW_])  << 16);
            u32 w3 = f2bf(src[6*HW_])  | ((u32)f2bf(src[7*HW_])  << 16);
            u32x4 q0 = {w0, w1, w2, w3};
            u32 v0 = f2bf(src[8*HW_])  | ((u32)f2bf(src[9*HW_])  << 16);
            u32 v1 = f2bf(src[10*HW_]) | ((u32)f2bf(src[11*HW_]) << 16);
            u32 v2 = f2bf(src[12*HW_]) | ((u32)f2bf(src[13*HW_]) << 16);
            u32 v3 = f2bf(src[14*HW_]) | ((u32)f2bf(src[15*HW_]) << 16);
            u32x4 q1 = {v0, v1, v2, v3};
            *(u32x4*)(lds +         p*16) = q0;
            *(u32x4*)(lds + REGB_ + p*16) = q1;
        }
        __syncthreads();

        const unsigned char* xh = lds + ks*REGB_;           // lane's k-half
        const unsigned char* ug = u_g + ((size_t)pass*RR_ << 10);

        u32x4 A0 = *(const u32x4*)(ug + aoff);
        u32x4 A1 = *(const u32x4*)(ug + (1 << 10) + aoff);
        int t = 0;
        for (int jx = 0; jx < R_; ++jx){
            int p0 = (pb + jx) * 16;
            u32x4 d0 = *(const u32x4*)(xh + p0);
            u32x4 d1 = *(const u32x4*)(xh + p0 +   PW_*16);
            u32x4 d2 = *(const u32x4*)(xh + p0 + 2*PW_*16);
            u32x4 d3 = *(const u32x4*)(xh + p0 + 3*PW_*16);
            #pragma unroll
            for (int i = 0; i < R_; ++i, ++t){
                int tn = t + 2; if (tn > RR_-1) tn = RR_-1;
                u32x4 An = *(const u32x4*)(ug + ((size_t)tn << 10) + aoff);
                u32x4 dn = d3;
                if (i < 11) dn = *(const u32x4*)(xh + p0 + (i+4)*PW_*16);
                MFMA(acc0, A0, d0);     // frag0: B = D(i)
                MFMA(acc1, A0, d2);     // frag1: B = D(i+2)
                A0 = A1; A1 = An;
                d0 = d1; d1 = d2; d2 = d3; d3 = dn;
            }
        }
    }

    // ---- epilogue: relu(num) * 1/||x_win||; D: col=lane&31,
    // row = (r&3) + 8*(r>>2) + 4*(lane>>5) ----
    int ow = ox + cx;
#define EPI(ACC, F) {                                                        \
        int oh = oy + 4*wv + rb + 2*(F);                                     \
        bool valid = (oh < HO_) && (ow < WO_);                               \
        float inv = 0.f;                                                     \
        if (valid) inv = inv_xn[(size_t)b*OHW_ + oh*WO_ + ow];               \
        float* ob = out + (size_t)b*K_*OHW_ + oh*WO_ + ow;                   \
        _Pragma("unroll")                                                    \
        for (int r = 0; r < 16; ++r){                                        \
            int kp = (r & 3) + 8*(r >> 2) + 4*ks;                            \
            if (valid) ob[(size_t)kp*OHW_] = fmaxf(ACC[r], 0.f) * inv;       \
        }                                                                    \
    }
    EPI(acc0, 0); EPI(acc1, 1);
#undef EPI
}

extern "C" void kernel_launch(void* const* d_in, const int* in_sizes, int n_in,
                              void* d_out, int out_size, void* d_ws, size_t ws_size,
                              hipStream_t stream) {
    const float* x = (const float*)d_in[0];
    const float* y = (const float*)d_in[1];
    float* out = (float*)d_out;
    unsigned char* ws = (unsigned char*)d_ws;

    unsigned char* u_g   = ws;                                   // 692224 B
    float*         s     = (float*)(ws + 692224);                // 1179648 B
    float*         invxn = (float*)(ws + 692224 + 1179648);      // 903168 B

    k_prep_y<<<K_, 256, 0, stream>>>(y, u_g);
    k_sq<<<(B_*HW_)/256, 256, 0, stream>>>(x, s);
    k_inv<<<(B_*OHW_)/256, 256, 0, stream>>>(s, invxn);

    k_main<<<B_*36, 256, LDS_BYTES, stream>>>(x, u_g, invxn, out);
}

// Round 6
// 241.469 us; speedup vs baseline: 1.0860x; 1.0860x over previous
//
#include <hip/hip_runtime.h>
#include <hip/hip_bf16.h>

#define B_   32
#define C_   64
#define H_   96
#define W_   96
#define K_   32
#define R_   13
#define HO_  84
#define WO_  84
#define HW_  (H_*W_)      // 9216
#define OHW_ (HO_*WO_)    // 7056
#define CRR_ (C_*R_*R_)   // 10816
#define RR_  (R_*R_)      // 169

#define TILE_ 16
#define PW_   28          // patch height/width = TILE_+12
#define NPIX_ (PW_*PW_)   // 784
#define REGB_ (NPIX_*16)  // 12544 bytes: one ks-half region (8ch/pixel), pixel-major
#define LDS_BYTES (2*REGB_) // 25088: 16ch/pass

typedef unsigned int u32;
typedef unsigned short u16;
typedef __attribute__((ext_vector_type(16))) float f32x16;
typedef __attribute__((ext_vector_type(4))) u32 u32x4;

static __device__ __forceinline__ u16 f2bf(float v){
    __hip_bfloat16 h = __float2bfloat16(v);  // RNE
    return *reinterpret_cast<u16*>(&h);
}

// D = A*B + D  (32x32x16 bf16)
#define MFMA(acc, a, b) asm("v_mfma_f32_32x32x16_bf16 %0, %1, %2, %0" \
                            : "+v"(acc) : "v"(a), "v"(b))

// ---------------- k1: y-norms + bf16 prototype tensor ----------------------
// u_g layout: [pass(4)][jx(13)][i(13)] slices of 1KB; within slice:
// byte = k*32 + ks*16 + e*2  where element e of half ks = channel cbase+ks*8+e.
// A-frag: lane(kpr,ks) reads 16B at slice + kpr*32 + ks*16.
__global__ void k_prep_y(const float* __restrict__ y, unsigned char* __restrict__ u_g){
    int k = blockIdx.x, tid = threadIdx.x;
    const float* yk = y + (size_t)k * CRR_;
    float ss = 0.f;
    for (int idx = tid; idx < CRR_; idx += 256){ float v = yk[idx]; ss += v*v; }
    for (int off = 32; off; off >>= 1) ss += __shfl_down(ss, off);
    __shared__ float red[4];
    if ((tid & 63) == 0) red[tid >> 6] = ss;
    __syncthreads();
    float inv = 1.f / fmaxf(sqrtf(red[0]+red[1]+red[2]+red[3]), 1e-9f);

    int c = tid & 63, grp = tid >> 6;                 // 64 c-lanes x 4 ij-groups
    int inoff = (k << 5) | ((c & 15) << 1);           // k*32 + (ks*8+e)*2
    for (int base = 0; base < RR_; base += 4){
        int ij = base + grp;
        if (ij < RR_){
            int i = ij / R_, jx = ij % R_;
            float v = yk[c*RR_ + ij] * inv;
            size_t slice = ((size_t)(c >> 4) * RR_ + jx*R_ + i) << 10;
            *(u16*)(u_g + slice + inoff) = f2bf(v);
        }
    }
}

// ---------------- k2: s[b,y,x] = sum_c x^2 (fp32 exact) --------------------
__global__ void k_sq(const float* __restrict__ x, float* __restrict__ s){
    int idx = blockIdx.x*256 + threadIdx.x;           // < 294912 exact
    int b = idx / HW_, r = idx % HW_;
    const float* xb = x + (size_t)b * C_ * HW_;
    float acc = 0.f;
    #pragma unroll
    for (int c = 0; c < C_; ++c){ float v = xb[(size_t)c*HW_ + r]; acc += v*v; }
    s[idx] = acc;
}

// ---------------- k3: inv_xn = 1/max(sqrt(13x13 box sum), eps) -------------
__global__ void k_inv(const float* __restrict__ s, float* __restrict__ inv_xn){
    int idx = blockIdx.x*256 + threadIdx.x;           // < 225792 exact
    int b = idx / OHW_, r = idx % OHW_;
    int oh = r / WO_, ow = r % WO_;
    const float* sb = s + (size_t)b*HW_ + oh*W_ + ow;
    float acc = 0.f;
    for (int i = 0; i < R_; ++i){
        #pragma unroll
        for (int j = 0; j < R_; ++j) acc += sb[i*W_ + j];
    }
    inv_xn[idx] = 1.f / fmaxf(sqrtf(acc), 1e-9f);
}

// ---------------- k_main: fused cosine-similarity conv ---------------------
// Block: 1 image x 16x16 tile, 256 thr (4 waves), 4 channel-passes (16ch).
// LDS 25088B; __launch_bounds__(256,4) -> VGPR cap 128 (NO spill; R4's (,6)
// cap 85 spilled) -> 4 blocks/CU = 16 waves/CU.
// Deep prefetch for the two measured latency chains:
//   A-window 4 taps (use-distance 4 iters ~ 280cyc > ~200cyc L1/L2 latency)
//   D-window 5 rows (frag1 use-distance 3 iters ~ 210cyc > ~120cyc LDS latency)
// 15 LDS b128 per jx per wave (rolling vertical reuse), 1 A-load per tap.
__launch_bounds__(256, 4)
__global__ void k_main(const float* __restrict__ x, const unsigned char* __restrict__ u_g,
                       const float* __restrict__ inv_xn, float* __restrict__ out){
    extern __shared__ unsigned char lds[];

    int bb = blockIdx.x;
    int b  = bb / 36;
    int tt = bb % 36;
    int oy = (tt / 6) * TILE_;
    int ox = (tt % 6) * TILE_;

    int tid  = threadIdx.x;
    int lane = tid & 63;
    int wv   = tid >> 6;        // 0..3
    int ks   = lane >> 5;       // k-half of MFMA operands
    int rb   = (lane >> 4) & 1; // row within a frag's 2-row strip
    int cx   = lane & 15;       // col
    int kpr  = lane & 31;       // prototype row for A-frag

    const float* xb = x + (size_t)b * C_ * HW_;
    int aoff = (kpr << 5) + (ks << 4);      // A lane offset within 1KB slice
    int pb   = (4*wv + rb) * PW_ + cx;      // frag0 base pixel; frag1 = +2*PW_

    f32x16 acc0 = {}, acc1 = {};

    for (int pass = 0; pass < 4; ++pass){
        if (pass) __syncthreads();          // prior-pass reads done
        int cbase = pass << 4;
        // ---- stage 16 channels: fp32 global -> bf16 LDS, pixel-major ----
        for (int p = tid; p < NPIX_; p += 256){
            int py = p / PW_, px = p % PW_;
            int gy = oy + py; if (gy > H_-1) gy = H_-1;  // clamp feeds only invalid outputs
            int gx = ox + px; if (gx > W_-1) gx = W_-1;
            const float* src = xb + (size_t)cbase*HW_ + gy*W_ + gx;
            u32 w0 = f2bf(src[0*HW_])  | ((u32)f2bf(src[1*HW_])  << 16);
            u32 w1 = f2bf(src[2*HW_])  | ((u32)f2bf(src[3*HW_])  << 16);
            u32 w2 = f2bf(src[4*HW_])  | ((u32)f2bf(src[5*HW_])  << 16);
            u32 w3 = f2bf(src[6*HW_])  | ((u32)f2bf(src[7*HW_])  << 16);
            u32x4 q0 = {w0, w1, w2, w3};
            u32 v0 = f2bf(src[8*HW_])  | ((u32)f2bf(src[9*HW_])  << 16);
            u32 v1 = f2bf(src[10*HW_]) | ((u32)f2bf(src[11*HW_]) << 16);
            u32 v2 = f2bf(src[12*HW_]) | ((u32)f2bf(src[13*HW_]) << 16);
            u32 v3 = f2bf(src[14*HW_]) | ((u32)f2bf(src[15*HW_]) << 16);
            u32x4 q1 = {v0, v1, v2, v3};
            *(u32x4*)(lds +         p*16) = q0;
            *(u32x4*)(lds + REGB_ + p*16) = q1;
        }
        __syncthreads();

        const unsigned char* xh = lds + ks*REGB_;           // lane's k-half
        const unsigned char* ug = u_g + ((size_t)pass*RR_ << 10);

        u32x4 A0 = *(const u32x4*)(ug              + aoff);
        u32x4 A1 = *(const u32x4*)(ug + (1 << 10)  + aoff);
        u32x4 A2 = *(const u32x4*)(ug + (2 << 10)  + aoff);
        u32x4 A3 = *(const u32x4*)(ug + (3 << 10)  + aoff);
        int t = 0;
        for (int jx = 0; jx < R_; ++jx){
            const unsigned char* col = xh + (pb + jx)*16;
            u32x4 d0 = *(const u32x4*)(col);
            u32x4 d1 = *(const u32x4*)(col +   PW_*16);
            u32x4 d2 = *(const u32x4*)(col + 2*PW_*16);
            u32x4 d3 = *(const u32x4*)(col + 3*PW_*16);
            u32x4 d4 = *(const u32x4*)(col + 4*PW_*16);
            #pragma unroll
            for (int i = 0; i < R_; ++i, ++t){
                int tn = t + 4; if (tn > RR_-1) tn = RR_-1;
                u32x4 An = *(const u32x4*)(ug + ((size_t)tn << 10) + aoff);
                u32x4 dn = d4;
                if (i < 10) dn = *(const u32x4*)(col + (i+5)*PW_*16);
                MFMA(acc0, A0, d0);     // frag0: B = D(i)
                MFMA(acc1, A0, d2);     // frag1: B = D(i+2)
                A0 = A1; A1 = A2; A2 = A3; A3 = An;
                d0 = d1; d1 = d2; d2 = d3; d3 = d4; d4 = dn;
            }
        }
    }

    // ---- epilogue: relu(num) * 1/||x_win||; D: col=lane&31,
    // row = (r&3) + 8*(r>>2) + 4*(lane>>5) ----
    int ow = ox + cx;
#define EPI(ACC, F) {                                                        \
        int oh = oy + 4*wv + rb + 2*(F);                                     \
        bool valid = (oh < HO_) && (ow < WO_);                               \
        float inv = 0.f;                                                     \
        if (valid) inv = inv_xn[(size_t)b*OHW_ + oh*WO_ + ow];               \
        float* ob = out + (size_t)b*K_*OHW_ + oh*WO_ + ow;                   \
        _Pragma("unroll")                                                    \
        for (int r = 0; r < 16; ++r){                                        \
            int kp = (r & 3) + 8*(r >> 2) + 4*ks;                            \
            if (valid) ob[(size_t)kp*OHW_] = fmaxf(ACC[r], 0.f) * inv;       \
        }                                                                    \
    }
    EPI(acc0, 0); EPI(acc1, 1);
#undef EPI
}

extern "C" void kernel_launch(void* const* d_in, const int* in_sizes, int n_in,
                              void* d_out, int out_size, void* d_ws, size_t ws_size,
                              hipStream_t stream) {
    const float* x = (const float*)d_in[0];
    const float* y = (const float*)d_in[1];
    float* out = (float*)d_out;
    unsigned char* ws = (unsigned char*)d_ws;

    unsigned char* u_g   = ws;                                   // 692224 B
    float*         s     = (float*)(ws + 692224);                // 1179648 B
    float*         invxn = (float*)(ws + 692224 + 1179648);      // 903168 B

    k_prep_y<<<K_, 256, 0, stream>>>(y, u_g);
    k_sq<<<(B_*HW_)/256, 256, 0, stream>>>(x, s);
    k_inv<<<(B_*OHW_)/256, 256, 0, stream>>>(s, invxn);

    k_main<<<B_*36, 256, LDS_BYTES, stream>>>(x, u_g, invxn, out);
}